// Round 1
// baseline (621.528 us; speedup 1.0000x reference)
//
#include <hip/hip_runtime.h>
#include <cstdint>
#include <cstddef>

// C[4096,4096] = sum_r input[r] @ weight[r]^T  == GEMM M=N=4096, K=8192, fp32 out.
// Phase 1: fp32 -> bf16 linear cast. R5: m13-style streaming — plain cached
//          loads (no nt), contiguous 128KB region per block, 16B packed stores.
//          (Previous nt + 4KB-strided version ran at ~1.5 TB/s = 4x off roofline.)
// Phase 2: m97-recipe bf16 MFMA GEMM (128x128 tile, BK=64, global_load_lds w=16)
//          + XOR bank swizzle (R2: conflicts 1e8 -> 0)
//          + XCD-aware 2x2 supertile swizzle (R4: L2 locality, FETCH 355->~230MB).

#define M_DIM 4096
#define N_DIM 4096
#define K_DIM 8192
#define K_LOCAL 1024
#define RANKS 8

typedef __bf16 bf16x8 __attribute__((ext_vector_type(8)));
typedef float f32x4 __attribute__((ext_vector_type(4)));

__device__ __forceinline__ unsigned short f2bf(float f) {
    unsigned int u = __float_as_uint(f);
    unsigned int r = (u + 0x7fffu + ((u >> 16) & 1u)) >> 16;
    return (unsigned short)r;
}

// ---------- Phase 1: linear fp32 -> bf16 cast ----------
// Each block owns a contiguous 32768-element (128KB fp32) region; 16 iters of
// {2x f32x4 load, pack, 1x 16B store} per thread. Plain loads (m13 pattern).
__global__ __launch_bounds__(256) void convert_cast(
    const float* __restrict__ srcA, unsigned short* __restrict__ dstA,
    const float* __restrict__ srcB, unsigned short* __restrict__ dstB,
    int blocks_per_tensor) {
    const float* src = srcA;
    unsigned short* dst = dstA;
    int b = blockIdx.x;
    if (b >= blocks_per_tensor) { b -= blocks_per_tensor; src = srcB; dst = dstB; }
    const size_t base = (size_t)b * 32768 + (size_t)threadIdx.x * 8;
#pragma unroll
    for (int it = 0; it < 16; ++it) {
        const size_t e = base + (size_t)it * 2048;
        f32x4 v0 = *(const f32x4*)(src + e);
        f32x4 v1 = *(const f32x4*)(src + e + 4);
        uint4 o;
        o.x = (unsigned)f2bf(v0.x) | ((unsigned)f2bf(v0.y) << 16);
        o.y = (unsigned)f2bf(v0.z) | ((unsigned)f2bf(v0.w) << 16);
        o.z = (unsigned)f2bf(v1.x) | ((unsigned)f2bf(v1.y) << 16);
        o.w = (unsigned)f2bf(v1.z) | ((unsigned)f2bf(v1.w) << 16);
        *(uint4*)(dst + e) = o;
    }
}

// ---------- Phase 2: bf16 MFMA GEMM over [R, rows, K_LOCAL] operands ----------
__device__ __forceinline__ void async_copy16(const unsigned short* g, unsigned short* l) {
    __builtin_amdgcn_global_load_lds(
        (const __attribute__((address_space(1))) void*)g,
        (__attribute__((address_space(3))) void*)l,
        16, 0, 0);
}

__global__ __launch_bounds__(256) void gemm_bf16(
    const unsigned short* __restrict__ A,  // [R, M, K_LOCAL] bf16
    const unsigned short* __restrict__ B,  // [R, N, K_LOCAL] bf16
    float* __restrict__ C) {               // [M, N] fp32
    __shared__ __align__(16) unsigned short As[128 * 64];
    __shared__ __align__(16) unsigned short Bs[128 * 64];

    const int tid = threadIdx.x;
    const int lane = tid & 63;
    const int wave = tid >> 6;
    const int wm = (wave >> 1) * 64;
    const int wn = (wave & 1) * 64;
    const int l15 = lane & 15;
    const int l4 = lane >> 4;

    // XCD-aware supertile swizzle: dispatch assumed round-robin (xcd = bid & 7).
    // Each XCD gets 2x2-block supertiles -> 4 co-resident blocks share
    // 2 A-strips + 2 B-strips in its 4MB L2.
    const int bid = blockIdx.x;            // 0..1023
    const int xcd = bid & 7;
    const int q = bid >> 3;                // 0..127
    const int st = (q >> 2) * 8 + xcd;     // supertile 0..255 (16x16 grid)
    const int pos = q & 3;
    const int bm0 = ((st >> 4) * 2 + (pos >> 1)) * 128;
    const int bn0 = ((st & 15) * 2 + (pos & 1)) * 128;

    // Staging: LDS chunk cc = p*256 + tid is (row = cc>>3, pos = cc&7).
    // XOR swizzle: chunk (row,pos) holds global 16B chunk col8 = pos ^ (row&7).
    const unsigned short* ga[4];
    const unsigned short* gb[4];
    int lo[4];
#pragma unroll
    for (int p = 0; p < 4; ++p) {
        int cc = p * 256 + tid;
        int row = cc >> 3;
        int cpos = cc & 7;
        int col = (cpos ^ (row & 7)) * 8;
        ga[p] = A + (size_t)(bm0 + row) * K_LOCAL + col;
        gb[p] = B + (size_t)(bn0 + row) * K_LOCAL + col;
        lo[p] = cc * 8;
    }

    const int swz0 = ((l4 + 0) ^ (l15 & 7)) * 8;  // ks = 0
    const int swz1 = ((l4 + 4) ^ (l15 & 7)) * 8;  // ks = 1
    const int a_row = (wm + l15) * 64;
    const int b_row = (wn + l15) * 64;

    f32x4 acc[4][4] = {};

    for (int r = 0; r < RANKS; ++r) {
        const size_t roff = (size_t)r * (M_DIM * (size_t)K_LOCAL);
        for (int kl = 0; kl < K_LOCAL; kl += 64) {
#pragma unroll
            for (int p = 0; p < 4; ++p) {
                async_copy16(ga[p] + roff + kl, &As[lo[p]]);
                async_copy16(gb[p] + roff + kl, &Bs[lo[p]]);
            }
            __syncthreads();
#pragma unroll
            for (int ks = 0; ks < 2; ++ks) {
                const int swz = ks ? swz1 : swz0;
                bf16x8 af[4], bfr[4];
#pragma unroll
                for (int i = 0; i < 4; ++i)
                    af[i] = *(const bf16x8*)&As[a_row + i * 16 * 64 + swz];
#pragma unroll
                for (int j = 0; j < 4; ++j)
                    bfr[j] = *(const bf16x8*)&Bs[b_row + j * 16 * 64 + swz];
#pragma unroll
                for (int i = 0; i < 4; ++i)
#pragma unroll
                    for (int j = 0; j < 4; ++j)
                        acc[i][j] = __builtin_amdgcn_mfma_f32_16x16x32_bf16(
                            af[i], bfr[j], acc[i][j], 0, 0, 0);
            }
            __syncthreads();
        }
    }

    // epilogue: C/D layout col = lane&15, row = (lane>>4)*4 + reg
#pragma unroll
    for (int i = 0; i < 4; ++i) {
        int row0 = bm0 + wm + i * 16 + l4 * 4;
#pragma unroll
        for (int j = 0; j < 4; ++j) {
            int col = bn0 + wn + j * 16 + l15;
#pragma unroll
            for (int r = 0; r < 4; ++r)
                C[(size_t)(row0 + r) * N_DIM + col] = acc[i][j][r];
        }
    }
}

// ---------- Fallback (ws too small): naive fp32 tiled GEMM ----------
__global__ void gemm_naive(const float* __restrict__ A, const float* __restrict__ B,
                           float* __restrict__ C) {
    __shared__ float As[16][17];
    __shared__ float Bs[16][17];
    int tx = threadIdx.x, ty = threadIdx.y;
    int m = blockIdx.y * 16 + ty;
    int n0 = blockIdx.x * 16;
    float accv = 0.f;
    for (int kt = 0; kt < K_DIM; kt += 16) {
        int r = kt >> 10;
        int k = (kt & 1023) + tx;
        As[ty][tx] = A[((size_t)r * M_DIM + m) * K_LOCAL + k];
        Bs[ty][tx] = B[((size_t)r * N_DIM + (n0 + ty)) * K_LOCAL + k];
        __syncthreads();
#pragma unroll
        for (int kk = 0; kk < 16; ++kk) accv += As[ty][kk] * Bs[tx][kk];
        __syncthreads();
    }
    C[(size_t)m * N_DIM + n0 + tx] = accv;
}

extern "C" void kernel_launch(void* const* d_in, const int* in_sizes, int n_in,
                              void* d_out, int out_size, void* d_ws, size_t ws_size,
                              hipStream_t stream) {
    const float* inp = (const float*)d_in[0];
    const float* wgt = (const float*)d_in[1];
    float* out = (float*)d_out;

    const size_t elems = (size_t)M_DIM * K_DIM;              // 33,554,432 per tensor
    const size_t need = 2 * elems * sizeof(unsigned short);  // 128 MiB

    if (ws_size >= need) {
        unsigned short* Abf = (unsigned short*)d_ws;
        unsigned short* Bbf = Abf + elems;
        const int bpt = (int)(elems / 32768);     // 1024 blocks per tensor
        convert_cast<<<bpt * 2, 256, 0, stream>>>(inp, Abf, wgt, Bbf, bpt);
        gemm_bf16<<<1024, 256, 0, stream>>>(Abf, Bbf, out);
    } else {
        dim3 grid(N_DIM / 16, M_DIM / 16);
        dim3 block(16, 16);
        gemm_naive<<<grid, block, 0, stream>>>(inp, wgt, out);
    }
}

// Round 2
// 570.779 us; speedup vs baseline: 1.0889x; 1.0889x over previous
//
#include <hip/hip_runtime.h>
#include <cstdint>
#include <cstddef>

// C[4096,4096] = sum_r input[r] @ weight[r]^T  == GEMM M=N=4096, K=8192, fp32 out.
// Phase 1: fp32 -> bf16 cast, R0 version restored (nontemporal loads keep the
//          dead fp32 source OUT of L3 so the bf16 workspace stays L3-resident
//          for the gemm; R1's cached loads cost the gemm +56us).
// Phase 2: R6: 256x256 8-phase counted-vmcnt GEMM (m201 port):
//          512 thr / 8 waves (2Mx4N), BK=64 staged as K-halves (4-deep ring),
//          vmcnt(4) counted waits (never 0 in main loop), raw s_barrier,
//          XOR swizzle on 64B LDS rows + pre-swizzled global src,
//          setprio(1) around 16-MFMA clusters, bijective XCD swizzle.

#define M_DIM 4096
#define N_DIM 4096
#define K_DIM 8192
#define K_LOCAL 1024
#define RANKS 8
#define NT 128  // K-tiles: RANKS * (K_LOCAL/64)

typedef __bf16 bf16x8 __attribute__((ext_vector_type(8)));
typedef float f32x4 __attribute__((ext_vector_type(4)));

__device__ __forceinline__ unsigned short f2bf(float f) {
    unsigned int u = __float_as_uint(f);
    unsigned int r = (u + 0x7fffu + ((u >> 16) & 1u)) >> 16;
    return (unsigned short)r;
}

// ---------- Phase 1: linear fp32 -> bf16 cast (R0 version) ----------
__global__ __launch_bounds__(256) void convert_cast(
    const float* __restrict__ srcA, unsigned short* __restrict__ dstA,
    const float* __restrict__ srcB, unsigned short* __restrict__ dstB,
    int blocks_per_tensor) {
    const float* src = srcA;
    unsigned short* dst = dstA;
    int b = blockIdx.x;
    if (b >= blocks_per_tensor) { b -= blocks_per_tensor; src = srcB; dst = dstB; }
    size_t base = (size_t)b * 4096 + threadIdx.x * 4;
#pragma unroll
    for (int i = 0; i < 4; ++i) {
        size_t e = base + i * 1024;
        f32x4 v = __builtin_nontemporal_load((const f32x4*)(src + e));
        ushort4 o;
        o.x = f2bf(v.x); o.y = f2bf(v.y); o.z = f2bf(v.z); o.w = f2bf(v.w);
        *(ushort4*)(dst + e) = o;
    }
}

// ---------- Phase 2: 256^2 8-phase bf16 MFMA GEMM ----------
__device__ __forceinline__ void async_copy16(const unsigned short* g, unsigned short* l) {
    __builtin_amdgcn_global_load_lds(
        (const __attribute__((address_space(1))) void*)g,
        (__attribute__((address_space(3))) void*)l,
        16, 0, 0);
}

#define WAIT_VM4() asm volatile("s_waitcnt vmcnt(4)" ::: "memory")
#define WAIT_VM0() asm volatile("s_waitcnt vmcnt(0)" ::: "memory")

__global__ __launch_bounds__(512, 2) void gemm_bf16(
    const unsigned short* __restrict__ A,  // [R, M, K_LOCAL] bf16
    const unsigned short* __restrict__ B,  // [R, N, K_LOCAL] bf16
    float* __restrict__ C) {               // [M, N] fp32
    // [buf][khalf][row][col] ; row = 64B -> XOR swizzle chunk ^= row&3
    __shared__ __align__(16) unsigned short As[2][2][256][32];
    __shared__ __align__(16) unsigned short Bs[2][2][256][32];

    const int tid = threadIdx.x;   // 0..511
    const int lane = tid & 63;
    const int wave = tid >> 6;     // 0..7
    const int l15 = lane & 15;
    const int l4 = lane >> 4;      // 0..3
    const int wm2 = wave >> 2;     // 0..1 -> row block *128
    const int wn4 = wave & 3;      // 0..3 -> col block *64

    // Bijective XCD swizzle: 256 blocks, each XCD owns a 4x8 tile sub-grid.
    const int bid = blockIdx.x;
    const int xcd = bid & 7;
    const int idx = bid >> 3;                       // 0..31
    const int trow = (xcd >> 1) * 4 + (idx >> 3);   // 0..15
    const int tcol = (xcd & 1) * 8 + (idx & 7);     // 0..15
    const int bm0 = trow * 256;
    const int bn0 = tcol * 256;

    // Staging geometry: one K-half = [256][32] = 16KiB, filled linearly as
    // 1024 chunks of 16B: li = wave*128 + issue*64 + lane; row = li>>2,
    // stored chunk cpos = li&3 holds global chunk g = cpos ^ (row&3).
    const unsigned short* gaBase[2];
    const unsigned short* gbBase[2];
    int ldsOff[2];
#pragma unroll
    for (int i = 0; i < 2; ++i) {
        int li = wave * 128 + i * 64 + lane;
        int row = li >> 2;
        int g = (li & 3) ^ (row & 3);
        gaBase[i] = A + (size_t)(bm0 + row) * K_LOCAL + g * 8;
        gbBase[i] = B + (size_t)(bn0 + row) * K_LOCAL + g * 8;
        ldsOff[i] = li * 8;  // ushort units = li*16 bytes
    }

    auto STAGE = [&](int t, int kh) {
        const size_t off = (size_t)(t >> 4) * ((size_t)M_DIM * K_LOCAL)
                         + (size_t)((t & 15) << 6) + (size_t)(kh << 5);
        const int buf = t & 1;
        unsigned short* la = &As[buf][kh][0][0];
        unsigned short* lb = &Bs[buf][kh][0][0];
#pragma unroll
        for (int i = 0; i < 2; ++i)
            async_copy16(gaBase[i] + off, la + ldsOff[i]);
#pragma unroll
        for (int i = 0; i < 2; ++i)
            async_copy16(gbBase[i] + off, lb + ldsOff[i]);
    };

    // Read addressing: A-frag m: row = wm2*128 + m*16 + l15, global k-chunk l4
    // -> stored at chunk l4 ^ (row&3) = l4 ^ (l15&3)  (row%16 == l15).
    const int swz_e = (l4 ^ (l15 & 3)) * 8;  // ushort units
    const int arow0 = wm2 * 128 + l15;
    const int brow0 = wn4 * 64 + l15;

    f32x4 acc[8][4] = {};

    auto CHALF = [&](int buf, int kk) {
        bf16x8 bv[4];
#pragma unroll
        for (int n = 0; n < 4; ++n)
            bv[n] = *(const bf16x8*)&Bs[buf][kk][brow0 + n * 16][swz_e];
        bf16x8 af[4];
#pragma unroll
        for (int m = 0; m < 4; ++m)
            af[m] = *(const bf16x8*)&As[buf][kk][arow0 + m * 16][swz_e];
        __builtin_amdgcn_s_setprio(1);
#pragma unroll
        for (int m = 0; m < 4; ++m)
#pragma unroll
            for (int n = 0; n < 4; ++n)
                acc[m][n] = __builtin_amdgcn_mfma_f32_16x16x32_bf16(
                    af[m], bv[n], acc[m][n], 0, 0, 0);
        __builtin_amdgcn_s_setprio(0);
        bf16x8 ag[4];
#pragma unroll
        for (int m = 0; m < 4; ++m)
            ag[m] = *(const bf16x8*)&As[buf][kk][arow0 + 64 + m * 16][swz_e];
        __builtin_amdgcn_s_setprio(1);
#pragma unroll
        for (int m = 0; m < 4; ++m)
#pragma unroll
            for (int n = 0; n < 4; ++n)
                acc[m + 4][n] = __builtin_amdgcn_mfma_f32_16x16x32_bf16(
                    ag[m], bv[n], acc[m + 4][n], 0, 0, 0);
        __builtin_amdgcn_s_setprio(0);
    };

    // Prologue: tile0 both halves + tile1 half0 (12 loads outstanding).
    STAGE(0, 0);
    STAGE(0, 1);
    STAGE(1, 0);
    WAIT_VM4();                      // tile0 kh0+kh1 landed
    __builtin_amdgcn_s_barrier();

    // Main loop. Issue pattern per tile t: S(t+1,kh1) at top, S(t+2,kh0) mid.
    // Every stage is issued >= 1 tile before its consuming phase; vmcnt(4)
    // at each half-tile boundary retires exactly the needed group.
    for (int t = 0; t < NT - 1; ++t) {
        const int cur = t & 1;
        STAGE(t + 1, 1);             // -> buf[cur^1], kh1
        CHALF(cur, 0);
        WAIT_VM4();
        __builtin_amdgcn_s_barrier();
        if (t < NT - 2) STAGE(t + 2, 0);  // -> buf[cur], kh0 (freed by barrier)
        CHALF(cur, 1);
        WAIT_VM4();
        __builtin_amdgcn_s_barrier();
    }
    // Peeled last tile (t = NT-1, buf 1): drain remaining kh1 with vmcnt(0).
    CHALF(1, 0);
    WAIT_VM0();
    __builtin_amdgcn_s_barrier();
    CHALF(1, 1);

    // Epilogue: C/D layout col = lane&15, row = (lane>>4)*4 + reg.
#pragma unroll
    for (int m = 0; m < 8; ++m) {
        int row0 = bm0 + wm2 * 128 + m * 16 + l4 * 4;
#pragma unroll
        for (int n = 0; n < 4; ++n) {
            int col = bn0 + wn4 * 64 + n * 16 + l15;
#pragma unroll
            for (int rr = 0; rr < 4; ++rr)
                C[(size_t)(row0 + rr) * N_DIM + col] = acc[m][n][rr];
        }
    }
}

// ---------- Fallback (ws too small): naive fp32 tiled GEMM ----------
__global__ void gemm_naive(const float* __restrict__ A, const float* __restrict__ B,
                           float* __restrict__ C) {
    __shared__ float As[16][17];
    __shared__ float Bs[16][17];
    int tx = threadIdx.x, ty = threadIdx.y;
    int m = blockIdx.y * 16 + ty;
    int n0 = blockIdx.x * 16;
    float accv = 0.f;
    for (int kt = 0; kt < K_DIM; kt += 16) {
        int r = kt >> 10;
        int k = (kt & 1023) + tx;
        As[ty][tx] = A[((size_t)r * M_DIM + m) * K_LOCAL + k];
        Bs[ty][tx] = B[((size_t)r * N_DIM + (n0 + ty)) * K_LOCAL + k];
        __syncthreads();
#pragma unroll
        for (int kk = 0; kk < 16; ++kk) accv += As[ty][kk] * Bs[tx][kk];
        __syncthreads();
    }
    C[(size_t)m * N_DIM + n0 + tx] = accv;
}

extern "C" void kernel_launch(void* const* d_in, const int* in_sizes, int n_in,
                              void* d_out, int out_size, void* d_ws, size_t ws_size,
                              hipStream_t stream) {
    const float* inp = (const float*)d_in[0];
    const float* wgt = (const float*)d_in[1];
    float* out = (float*)d_out;

    const size_t elems = (size_t)M_DIM * K_DIM;              // 33,554,432 per tensor
    const size_t need = 2 * elems * sizeof(unsigned short);  // 128 MiB

    if (ws_size >= need) {
        unsigned short* Abf = (unsigned short*)d_ws;
        unsigned short* Bbf = Abf + elems;
        const int bpt = (int)(elems / 4096);      // 8192 blocks per tensor
        convert_cast<<<bpt * 2, 256, 0, stream>>>(inp, Abf, wgt, Bbf, bpt);
        gemm_bf16<<<256, 512, 0, stream>>>(Abf, Bbf, out);
    } else {
        dim3 grid(N_DIM / 16, M_DIM / 16);
        dim3 block(16, 16);
        gemm_naive<<<grid, block, 0, stream>>>(inp, wgt, out);
    }
}

// Round 3
// 562.809 us; speedup vs baseline: 1.1043x; 1.0142x over previous
//
#include <hip/hip_runtime.h>
#include <cstdint>
#include <cstddef>

// C[4096,4096] = sum_r input[r] @ weight[r]^T  == GEMM M=N=4096, K=8192, fp32 out.
// Phase 1: fp32 -> bf16 cast, R0 version (nontemporal loads keep the dead fp32
//          source OUT of L3 so the bf16 workspace stays L3-resident; R1's
//          cached-load variant cost the gemm +56us).
// Phase 2: R7: 256x256 counted-vmcnt GEMM. R2's swizzle (chunk ^= row&3) was a
//          4-way bank conflict: 64B rows -> bank group = chunk + 4*(row&1), and
//          XOR bit0 duplicated the parity bit (2.5e7 conflicts, MfmaUtil 35%).
//          Fix: chunk ^= (row>>1)&3 -> each quarter-wave hits all 8 bank
//          groups exactly 2x (2-way = free, m136).

#define M_DIM 4096
#define N_DIM 4096
#define K_DIM 8192
#define K_LOCAL 1024
#define RANKS 8
#define NT 128  // K-tiles: RANKS * (K_LOCAL/64)

typedef __bf16 bf16x8 __attribute__((ext_vector_type(8)));
typedef float f32x4 __attribute__((ext_vector_type(4)));

__device__ __forceinline__ unsigned short f2bf(float f) {
    unsigned int u = __float_as_uint(f);
    unsigned int r = (u + 0x7fffu + ((u >> 16) & 1u)) >> 16;
    return (unsigned short)r;
}

// ---------- Phase 1: linear fp32 -> bf16 cast (R0 version) ----------
__global__ __launch_bounds__(256) void convert_cast(
    const float* __restrict__ srcA, unsigned short* __restrict__ dstA,
    const float* __restrict__ srcB, unsigned short* __restrict__ dstB,
    int blocks_per_tensor) {
    const float* src = srcA;
    unsigned short* dst = dstA;
    int b = blockIdx.x;
    if (b >= blocks_per_tensor) { b -= blocks_per_tensor; src = srcB; dst = dstB; }
    size_t base = (size_t)b * 4096 + threadIdx.x * 4;
#pragma unroll
    for (int i = 0; i < 4; ++i) {
        size_t e = base + i * 1024;
        f32x4 v = __builtin_nontemporal_load((const f32x4*)(src + e));
        ushort4 o;
        o.x = f2bf(v.x); o.y = f2bf(v.y); o.z = f2bf(v.z); o.w = f2bf(v.w);
        *(ushort4*)(dst + e) = o;
    }
}

// ---------- Phase 2: 256^2 counted-vmcnt bf16 MFMA GEMM ----------
__device__ __forceinline__ void async_copy16(const unsigned short* g, unsigned short* l) {
    __builtin_amdgcn_global_load_lds(
        (const __attribute__((address_space(1))) void*)g,
        (__attribute__((address_space(3))) void*)l,
        16, 0, 0);
}

#define WAIT_VM4() asm volatile("s_waitcnt vmcnt(4)" ::: "memory")
#define WAIT_VM0() asm volatile("s_waitcnt vmcnt(0)" ::: "memory")

__global__ __launch_bounds__(512, 2) void gemm_bf16(
    const unsigned short* __restrict__ A,  // [R, M, K_LOCAL] bf16
    const unsigned short* __restrict__ B,  // [R, N, K_LOCAL] bf16
    float* __restrict__ C) {               // [M, N] fp32
    // [buf][khalf][row][col] ; row = 64B. Bank group of a 16B chunk is
    // chunk + 4*(row&1); swizzle chunk ^= (row>>1)&3 (conflict-free, see R7).
    __shared__ __align__(16) unsigned short As[2][2][256][32];
    __shared__ __align__(16) unsigned short Bs[2][2][256][32];

    const int tid = threadIdx.x;   // 0..511
    const int lane = tid & 63;
    const int wave = tid >> 6;     // 0..7
    const int l15 = lane & 15;
    const int l4 = lane >> 4;      // 0..3
    const int wm2 = wave >> 2;     // 0..1 -> row block *128
    const int wn4 = wave & 3;      // 0..3 -> col block *64

    // Bijective XCD swizzle: 256 blocks, each XCD owns a 4x8 tile sub-grid.
    const int bid = blockIdx.x;
    const int xcd = bid & 7;
    const int idx = bid >> 3;                       // 0..31
    const int trow = (xcd >> 1) * 4 + (idx >> 3);   // 0..15
    const int tcol = (xcd & 1) * 8 + (idx & 7);     // 0..15
    const int bm0 = trow * 256;
    const int bn0 = tcol * 256;

    // Staging geometry: one K-half = [256][32] = 16KiB, filled linearly as
    // 1024 chunks of 16B: li = wave*128 + issue*64 + lane; row = li>>2,
    // stored chunk cpos = li&3 holds global chunk g = cpos ^ ((row>>1)&3)
    //   = (li&3) ^ ((li>>3)&3).
    const unsigned short* gaBase[2];
    const unsigned short* gbBase[2];
    int ldsOff[2];
#pragma unroll
    for (int i = 0; i < 2; ++i) {
        int li = wave * 128 + i * 64 + lane;
        int row = li >> 2;
        int g = (li & 3) ^ ((li >> 3) & 3);
        gaBase[i] = A + (size_t)(bm0 + row) * K_LOCAL + g * 8;
        gbBase[i] = B + (size_t)(bn0 + row) * K_LOCAL + g * 8;
        ldsOff[i] = li * 8;  // ushort units = li*16 bytes
    }

    auto STAGE = [&](int t, int kh) {
        const size_t off = (size_t)(t >> 4) * ((size_t)M_DIM * K_LOCAL)
                         + (size_t)((t & 15) << 6) + (size_t)(kh << 5);
        const int buf = t & 1;
        unsigned short* la = &As[buf][kh][0][0];
        unsigned short* lb = &Bs[buf][kh][0][0];
#pragma unroll
        for (int i = 0; i < 2; ++i)
            async_copy16(gaBase[i] + off, la + ldsOff[i]);
#pragma unroll
        for (int i = 0; i < 2; ++i)
            async_copy16(gbBase[i] + off, lb + ldsOff[i]);
    };

    // Read addressing: row r = <multiple of 16 or 64> + l15 everywhere, so
    // (r>>1)&3 == (l15>>1)&3. Stored chunk for global chunk l4:
    const int swz_e = (l4 ^ ((l15 >> 1) & 3)) * 8;  // ushort units
    const int arow0 = wm2 * 128 + l15;
    const int brow0 = wn4 * 64 + l15;

    f32x4 acc[8][4] = {};

    auto CHALF = [&](int buf, int kk) {
        bf16x8 bv[4];
#pragma unroll
        for (int n = 0; n < 4; ++n)
            bv[n] = *(const bf16x8*)&Bs[buf][kk][brow0 + n * 16][swz_e];
        bf16x8 af[4];
#pragma unroll
        for (int m = 0; m < 4; ++m)
            af[m] = *(const bf16x8*)&As[buf][kk][arow0 + m * 16][swz_e];
        __builtin_amdgcn_s_setprio(1);
#pragma unroll
        for (int m = 0; m < 4; ++m)
#pragma unroll
            for (int n = 0; n < 4; ++n)
                acc[m][n] = __builtin_amdgcn_mfma_f32_16x16x32_bf16(
                    af[m], bv[n], acc[m][n], 0, 0, 0);
        __builtin_amdgcn_s_setprio(0);
        bf16x8 ag[4];
#pragma unroll
        for (int m = 0; m < 4; ++m)
            ag[m] = *(const bf16x8*)&As[buf][kk][arow0 + 64 + m * 16][swz_e];
        __builtin_amdgcn_s_setprio(1);
#pragma unroll
        for (int m = 0; m < 4; ++m)
#pragma unroll
            for (int n = 0; n < 4; ++n)
                acc[m + 4][n] = __builtin_amdgcn_mfma_f32_16x16x32_bf16(
                    ag[m], bv[n], acc[m + 4][n], 0, 0, 0);
        __builtin_amdgcn_s_setprio(0);
    };

    // Prologue: tile0 both halves + tile1 half0 (12 loads/wave outstanding).
    STAGE(0, 0);
    STAGE(0, 1);
    STAGE(1, 0);
    WAIT_VM4();                      // tile0 kh0+kh1 landed
    __builtin_amdgcn_s_barrier();

    // Main loop. Issue pattern per tile t: S(t+1,kh1) at top, S(t+2,kh0) mid.
    // Every stage is issued >= 1 tile before its consuming phase; vmcnt(4)
    // at each half-tile boundary retires exactly the needed group.
    for (int t = 0; t < NT - 1; ++t) {
        const int cur = t & 1;
        STAGE(t + 1, 1);             // -> buf[cur^1], kh1
        CHALF(cur, 0);
        WAIT_VM4();
        __builtin_amdgcn_s_barrier();
        if (t < NT - 2) STAGE(t + 2, 0);  // -> buf[cur], kh0 (freed by barrier)
        CHALF(cur, 1);
        WAIT_VM4();
        __builtin_amdgcn_s_barrier();
    }
    // Peeled last tile (t = NT-1, buf 1): drain remaining kh1 with vmcnt(0).
    CHALF(1, 0);
    WAIT_VM0();
    __builtin_amdgcn_s_barrier();
    CHALF(1, 1);

    // Epilogue: C/D layout col = lane&15, row = (lane>>4)*4 + reg.
#pragma unroll
    for (int m = 0; m < 8; ++m) {
        int row0 = bm0 + wm2 * 128 + m * 16 + l4 * 4;
#pragma unroll
        for (int n = 0; n < 4; ++n) {
            int col = bn0 + wn4 * 64 + n * 16 + l15;
#pragma unroll
            for (int rr = 0; rr < 4; ++rr)
                C[(size_t)(row0 + rr) * N_DIM + col] = acc[m][n][rr];
        }
    }
}

// ---------- Fallback (ws too small): naive fp32 tiled GEMM ----------
__global__ void gemm_naive(const float* __restrict__ A, const float* __restrict__ B,
                           float* __restrict__ C) {
    __shared__ float As[16][17];
    __shared__ float Bs[16][17];
    int tx = threadIdx.x, ty = threadIdx.y;
    int m = blockIdx.y * 16 + ty;
    int n0 = blockIdx.x * 16;
    float accv = 0.f;
    for (int kt = 0; kt < K_DIM; kt += 16) {
        int r = kt >> 10;
        int k = (kt & 1023) + tx;
        As[ty][tx] = A[((size_t)r * M_DIM + m) * K_LOCAL + k];
        Bs[ty][tx] = B[((size_t)r * N_DIM + (n0 + ty)) * K_LOCAL + k];
        __syncthreads();
#pragma unroll
        for (int kk = 0; kk < 16; ++kk) accv += As[ty][kk] * Bs[tx][kk];
        __syncthreads();
    }
    C[(size_t)m * N_DIM + n0 + tx] = accv;
}

extern "C" void kernel_launch(void* const* d_in, const int* in_sizes, int n_in,
                              void* d_out, int out_size, void* d_ws, size_t ws_size,
                              hipStream_t stream) {
    const float* inp = (const float*)d_in[0];
    const float* wgt = (const float*)d_in[1];
    float* out = (float*)d_out;

    const size_t elems = (size_t)M_DIM * K_DIM;              // 33,554,432 per tensor
    const size_t need = 2 * elems * sizeof(unsigned short);  // 128 MiB

    if (ws_size >= need) {
        unsigned short* Abf = (unsigned short*)d_ws;
        unsigned short* Bbf = Abf + elems;
        const int bpt = (int)(elems / 4096);      // 8192 blocks per tensor
        convert_cast<<<bpt * 2, 256, 0, stream>>>(inp, Abf, wgt, Bbf, bpt);
        gemm_bf16<<<256, 512, 0, stream>>>(Abf, Bbf, out);
    } else {
        dim3 grid(N_DIM / 16, M_DIM / 16);
        dim3 block(16, 16);
        gemm_naive<<<grid, block, 0, stream>>>(inp, wgt, out);
    }
}

// Round 4
// 521.535 us; speedup vs baseline: 1.1917x; 1.0791x over previous
//
#include <hip/hip_runtime.h>
#include <cstdint>
#include <cstddef>

// C[4096,4096] = sum_r input[r] @ weight[r]^T  == GEMM M=N=4096, K=8192, fp32 out.
// Phase 1: fp32 -> bf16 cast, R0 version (nontemporal loads keep the dead fp32
//          source OUT of L3 so the bf16 workspace stays L3-resident).
// Phase 2: R8: faithful m201 8-phase schedule. R3's coarse split (32-MFMA
//          clusters, 2 waits/K-tile) plateaued at 860 TF / 38% MfmaUtil (the
//          m196 "coarse phase-split" regression). Now: per K-tile 4 phases x
//          16 MFMA (one C-quadrant), per-phase {ds_read group; 1 half-tensor
//          stage unit; bar; lgkm0; prio1; MFMA16; prio0; bar}; counted
//          vmcnt(4) ONLY at phases 4/8; LDS [buf][half][128][64] with the
//          R0-proven chunk^=(row&7) swizzle (0 conflicts at 128B rows).

#define M_DIM 4096
#define N_DIM 4096
#define K_DIM 8192
#define K_LOCAL 1024
#define RANKS 8
#define NT 128  // K-tiles: RANKS * (K_LOCAL/64)

typedef __bf16 bf16x8 __attribute__((ext_vector_type(8)));
typedef float f32x4 __attribute__((ext_vector_type(4)));

__device__ __forceinline__ unsigned short f2bf(float f) {
    unsigned int u = __float_as_uint(f);
    unsigned int r = (u + 0x7fffu + ((u >> 16) & 1u)) >> 16;
    return (unsigned short)r;
}

// ---------- Phase 1: linear fp32 -> bf16 cast (R0 version) ----------
__global__ __launch_bounds__(256) void convert_cast(
    const float* __restrict__ srcA, unsigned short* __restrict__ dstA,
    const float* __restrict__ srcB, unsigned short* __restrict__ dstB,
    int blocks_per_tensor) {
    const float* src = srcA;
    unsigned short* dst = dstA;
    int b = blockIdx.x;
    if (b >= blocks_per_tensor) { b -= blocks_per_tensor; src = srcB; dst = dstB; }
    size_t base = (size_t)b * 4096 + threadIdx.x * 4;
#pragma unroll
    for (int i = 0; i < 4; ++i) {
        size_t e = base + i * 1024;
        f32x4 v = __builtin_nontemporal_load((const f32x4*)(src + e));
        ushort4 o;
        o.x = f2bf(v.x); o.y = f2bf(v.y); o.z = f2bf(v.z); o.w = f2bf(v.w);
        *(ushort4*)(dst + e) = o;
    }
}

// ---------- Phase 2: 256^2 8-phase counted-vmcnt bf16 MFMA GEMM ----------
__device__ __forceinline__ void async_copy16(const unsigned short* g, unsigned short* l) {
    __builtin_amdgcn_global_load_lds(
        (const __attribute__((address_space(1))) void*)g,
        (__attribute__((address_space(3))) void*)l,
        16, 0, 0);
}

#define VM4()   asm volatile("s_waitcnt vmcnt(4)" ::: "memory")
#define LGKM0() asm volatile("s_waitcnt lgkmcnt(0)" ::: "memory")
#define BAR()   __builtin_amdgcn_s_barrier()

__global__ __launch_bounds__(512, 2) void gemm_bf16(
    const unsigned short* __restrict__ A,  // [R, M, K_LOCAL] bf16
    const unsigned short* __restrict__ B,  // [R, N, K_LOCAL] bf16
    float* __restrict__ C) {               // [M, N] fp32
    // Per-tensor-half regions: [buf][rowhalf][128 rows][64 k] (128B rows).
    // 16B chunk c of row r stored at chunk c ^ (r & 7)  (R0-proven, 0 conflicts).
    __shared__ __align__(16) unsigned short As[2][2][128][64];
    __shared__ __align__(16) unsigned short Bs[2][2][128][64];

    const int tid = threadIdx.x;   // 0..511
    const int lane = tid & 63;
    const int wave = tid >> 6;     // 0..7
    const int l15 = lane & 15;
    const int l4 = lane >> 4;      // 0..3
    const int wm2 = wave >> 2;     // 0..1 -> row block *128 (also = A half)
    const int wn4 = wave & 3;      // 0..3 -> col block *64

    // Bijective XCD swizzle: 256 blocks, each XCD owns a 4x8 tile sub-grid.
    const int bid = blockIdx.x;
    const int xcd = bid & 7;
    const int idx = bid >> 3;                       // 0..31
    const int trow = (xcd >> 1) * 4 + (idx >> 3);   // 0..15
    const int tcol = (xcd & 1) * 8 + (idx & 7);     // 0..15
    const int bm0 = trow * 256;
    const int bn0 = tcol * 256;

    // Stage unit = one tensor-half: 128 rows x 64 k x 2B = 16KB = 1024 chunks;
    // li = i*512 + tid (i=0,1): row = li>>3, cpos = li&7, global chunk
    // g = cpos ^ (row & 7). LDS dst is linear (li*16B).
    const unsigned short* gA[2];
    const unsigned short* gB[2];
    int lo[2];
#pragma unroll
    for (int i = 0; i < 2; ++i) {
        int li = i * 512 + tid;
        int row = li >> 3;
        int g = (li & 7) ^ (row & 7);
        gA[i] = A + (size_t)(bm0 + row) * K_LOCAL + g * 8;
        gB[i] = B + (size_t)(bn0 + row) * K_LOCAL + g * 8;
        lo[i] = li * 8;  // ushort units
    }

    auto stageA = [&](int t, int buf, int h) {
        const size_t off = (size_t)(t >> 4) * ((size_t)M_DIM * K_LOCAL)
                         + (size_t)((t & 15) << 6) + (size_t)h * (128 * K_LOCAL);
        unsigned short* l = &As[buf][h][0][0];
        async_copy16(gA[0] + off, l + lo[0]);
        async_copy16(gA[1] + off, l + lo[1]);
    };
    auto stageB = [&](int t, int buf, int h) {
        const size_t off = (size_t)(t >> 4) * ((size_t)M_DIM * K_LOCAL)
                         + (size_t)((t & 15) << 6) + (size_t)h * (128 * K_LOCAL);
        unsigned short* l = &Bs[buf][h][0][0];
        async_copy16(gB[0] + off, l + lo[0]);
        async_copy16(gB[1] + off, l + lo[1]);
    };

    // Fragment reads: k-chunk c = ks*4 + l4, stored at c ^ (row&7); all frag
    // rows are <mult of 16> + l15, so row&7 == l15&7.
    const int swzk0 = ((l4 + 0) ^ (l15 & 7)) * 8;  // ks = 0
    const int swzk1 = ((l4 + 4) ^ (l15 & 7)) * 8;  // ks = 1
    const int hb = wn4 >> 1;                        // B half for this wave
    const int brow_base = (wn4 & 1) * 64 + l15;     // B row within half

    f32x4 acc[8][4] = {};
    bf16x8 aR[8], a1R[8], b0R[4], b1R[4];

    auto LDA = [&](bf16x8* dst, int buf, int mh) {
#pragma unroll
        for (int m = 0; m < 4; ++m) {
            const unsigned short* rp = &As[buf][wm2][mh * 64 + m * 16 + l15][0];
            dst[m * 2 + 0] = *(const bf16x8*)(rp + swzk0);
            dst[m * 2 + 1] = *(const bf16x8*)(rp + swzk1);
        }
    };
    auto LDB = [&](bf16x8* dst, int buf, int nh) {
#pragma unroll
        for (int n = 0; n < 2; ++n) {
            const unsigned short* rp = &Bs[buf][hb][brow_base + nh * 32 + n * 16][0];
            dst[n * 2 + 0] = *(const bf16x8*)(rp + swzk0);
            dst[n * 2 + 1] = *(const bf16x8*)(rp + swzk1);
        }
    };
    auto MFMA16 = [&](const bf16x8* a, const bf16x8* b, int mh, int nh) {
        __builtin_amdgcn_s_setprio(1);
#pragma unroll
        for (int m = 0; m < 4; ++m)
#pragma unroll
            for (int n = 0; n < 2; ++n)
#pragma unroll
                for (int ks = 0; ks < 2; ++ks)
                    acc[mh * 4 + m][nh * 2 + n] = __builtin_amdgcn_mfma_f32_16x16x32_bf16(
                        a[m * 2 + ks], b[n * 2 + ks], acc[mh * 4 + m][nh * 2 + n], 0, 0, 0);
        __builtin_amdgcn_s_setprio(0);
    };

    // Prologue: tile0 all 4 units + B units of tile1 (12 loads); vmcnt(4)
    // leaves B1(1),B0(1) in flight — matches steady state entering Ph1.
    stageA(0, 0, 0); stageA(0, 0, 1); stageB(0, 0, 0); stageB(0, 0, 1);
    stageB(1, 1, 1); stageB(1, 1, 0);
    VM4(); BAR();

    for (int i = 0; i < NT / 2; ++i) {
        const int t = 2 * i;
        const int t1 = t + 1;
        const int t2 = (t + 2) & (NT - 1);
        const int t3 = (t + 3) & (NT - 1);
        // Ph1: Q00 of t (buf0); stage A0(t1)->buf1
        LDA(aR, 0, 0); LDB(b0R, 0, 0); stageA(t1, 1, 0);
        BAR(); LGKM0(); MFMA16(aR, b0R, 0, 0); BAR();
        // Ph2: Q01; stage A1(t1)->buf1
        LDB(b1R, 0, 1); stageA(t1, 1, 1);
        BAR(); LGKM0(); MFMA16(aR, b1R, 0, 1); BAR();
        // Ph3: Q10; stage B1(t2)->buf0 (buf0.B1 free after Ph2)
        LDA(a1R, 0, 1); stageB(t2, 0, 1);
        BAR(); LGKM0(); MFMA16(a1R, b0R, 1, 0); BAR();
        // Ph4: Q11 (all regs live); stage B0(t2)->buf0; W1 = vmcnt(4)
        stageB(t2, 0, 0);
        BAR(); MFMA16(a1R, b1R, 1, 1); VM4(); BAR();
        // Ph5: Q00 of t1 (buf1); stage A0(t2)->buf0 (buf0.A free after Ph3)
        LDA(aR, 1, 0); LDB(b0R, 1, 0); stageA(t2, 0, 0);
        BAR(); LGKM0(); MFMA16(aR, b0R, 0, 0); BAR();
        // Ph6: Q01; stage A1(t2)->buf0
        LDB(b1R, 1, 1); stageA(t2, 0, 1);
        BAR(); LGKM0(); MFMA16(aR, b1R, 0, 1); BAR();
        // Ph7: Q10; stage B1(t3)->buf1 (buf1.B1 free after Ph6)
        LDA(a1R, 1, 1); stageB(t3, 1, 1);
        BAR(); LGKM0(); MFMA16(a1R, b0R, 1, 0); BAR();
        // Ph8: Q11; stage B0(t3)->buf1; W2 = vmcnt(4)
        stageB(t3, 1, 0);
        BAR(); MFMA16(a1R, b1R, 1, 1); VM4(); BAR();
    }

    // Epilogue: C/D layout col = lane&15, row = (lane>>4)*4 + reg.
#pragma unroll
    for (int m = 0; m < 8; ++m) {
        int row0 = bm0 + wm2 * 128 + m * 16 + l4 * 4;
#pragma unroll
        for (int n = 0; n < 4; ++n) {
            int col = bn0 + wn4 * 64 + n * 16 + l15;
#pragma unroll
            for (int rr = 0; rr < 4; ++rr)
                C[(size_t)(row0 + rr) * N_DIM + col] = acc[m][n][rr];
        }
    }
}

// ---------- Fallback (ws too small): naive fp32 tiled GEMM ----------
__global__ void gemm_naive(const float* __restrict__ A, const float* __restrict__ B,
                           float* __restrict__ C) {
    __shared__ float As[16][17];
    __shared__ float Bs[16][17];
    int tx = threadIdx.x, ty = threadIdx.y;
    int m = blockIdx.y * 16 + ty;
    int n0 = blockIdx.x * 16;
    float accv = 0.f;
    for (int kt = 0; kt < K_DIM; kt += 16) {
        int r = kt >> 10;
        int k = (kt & 1023) + tx;
        As[ty][tx] = A[((size_t)r * M_DIM + m) * K_LOCAL + k];
        Bs[ty][tx] = B[((size_t)r * N_DIM + (n0 + ty)) * K_LOCAL + k];
        __syncthreads();
#pragma unroll
        for (int kk = 0; kk < 16; ++kk) accv += As[ty][kk] * Bs[tx][kk];
        __syncthreads();
    }
    C[(size_t)m * N_DIM + n0 + tx] = accv;
}

extern "C" void kernel_launch(void* const* d_in, const int* in_sizes, int n_in,
                              void* d_out, int out_size, void* d_ws, size_t ws_size,
                              hipStream_t stream) {
    const float* inp = (const float*)d_in[0];
    const float* wgt = (const float*)d_in[1];
    float* out = (float*)d_out;

    const size_t elems = (size_t)M_DIM * K_DIM;              // 33,554,432 per tensor
    const size_t need = 2 * elems * sizeof(unsigned short);  // 128 MiB

    if (ws_size >= need) {
        unsigned short* Abf = (unsigned short*)d_ws;
        unsigned short* Bbf = Abf + elems;
        const int bpt = (int)(elems / 4096);      // 8192 blocks per tensor
        convert_cast<<<bpt * 2, 256, 0, stream>>>(inp, Abf, wgt, Bbf, bpt);
        gemm_bf16<<<256, 512, 0, stream>>>(Abf, Bbf, out);
    } else {
        dim3 grid(N_DIM / 16, M_DIM / 16);
        dim3 block(16, 16);
        gemm_naive<<<grid, block, 0, stream>>>(inp, wgt, out);
    }
}

// Round 5
// 518.163 us; speedup vs baseline: 1.1995x; 1.0065x over previous
//
#include <hip/hip_runtime.h>
#include <cstdint>
#include <cstddef>

// C[4096,4096] = sum_r input[r] @ weight[r]^T  == GEMM M=N=4096, K=8192, fp32 out.
// Phase 1: fp32 -> bf16 cast, R0 version (nontemporal loads keep the dead fp32
//          source OUT of L3 so the bf16 workspace stays L3-resident).
// Phase 2: R9: pipelined 8-phase GEMM. R4 serialized LDS reads with MFMA
//          (each phase: reads -> lgkm0 -> MFMA => pipes ping-pong; 978 TF).
//          Now phase p issues ds_reads for quadrant p+1 UNDER the MFMAs of
//          quadrant p (frags loaded last phase, no in-phase lgkm dep).
//          Stage slots re-derived: P0/P1=A(t1), P2/P3=B(t2), P4/P5=A(t2),
//          P6/P7=B(t3); counted vmcnt(4) at P3/P7 tops only.

#define M_DIM 4096
#define N_DIM 4096
#define K_DIM 8192
#define K_LOCAL 1024
#define RANKS 8
#define NT 128  // K-tiles: RANKS * (K_LOCAL/64)

typedef __bf16 bf16x8 __attribute__((ext_vector_type(8)));
typedef float f32x4 __attribute__((ext_vector_type(4)));

__device__ __forceinline__ unsigned short f2bf(float f) {
    unsigned int u = __float_as_uint(f);
    unsigned int r = (u + 0x7fffu + ((u >> 16) & 1u)) >> 16;
    return (unsigned short)r;
}

// ---------- Phase 1: linear fp32 -> bf16 cast (R0 version) ----------
__global__ __launch_bounds__(256) void convert_cast(
    const float* __restrict__ srcA, unsigned short* __restrict__ dstA,
    const float* __restrict__ srcB, unsigned short* __restrict__ dstB,
    int blocks_per_tensor) {
    const float* src = srcA;
    unsigned short* dst = dstA;
    int b = blockIdx.x;
    if (b >= blocks_per_tensor) { b -= blocks_per_tensor; src = srcB; dst = dstB; }
    size_t base = (size_t)b * 4096 + threadIdx.x * 4;
#pragma unroll
    for (int i = 0; i < 4; ++i) {
        size_t e = base + i * 1024;
        f32x4 v = __builtin_nontemporal_load((const f32x4*)(src + e));
        ushort4 o;
        o.x = f2bf(v.x); o.y = f2bf(v.y); o.z = f2bf(v.z); o.w = f2bf(v.w);
        *(ushort4*)(dst + e) = o;
    }
}

// ---------- Phase 2: 256^2 pipelined 8-phase bf16 MFMA GEMM ----------
__device__ __forceinline__ void async_copy16(const unsigned short* g, unsigned short* l) {
    __builtin_amdgcn_global_load_lds(
        (const __attribute__((address_space(1))) void*)g,
        (__attribute__((address_space(3))) void*)l,
        16, 0, 0);
}

#define VM4() asm volatile("s_waitcnt vmcnt(4)" ::: "memory")
#define VM0() asm volatile("s_waitcnt vmcnt(0)" ::: "memory")
#define BAR() __builtin_amdgcn_s_barrier()

__global__ __launch_bounds__(512, 2) void gemm_bf16(
    const unsigned short* __restrict__ A,  // [R, M, K_LOCAL] bf16
    const unsigned short* __restrict__ B,  // [R, N, K_LOCAL] bf16
    float* __restrict__ C) {               // [M, N] fp32
    // Per-tensor-half regions: [buf][rowhalf][128 rows][64 k] (128B rows).
    // 16B chunk c of row r stored at chunk c ^ (r & 7) (0 conflicts).
    __shared__ __align__(16) unsigned short As[2][2][128][64];
    __shared__ __align__(16) unsigned short Bs[2][2][128][64];

    const int tid = threadIdx.x;   // 0..511
    const int lane = tid & 63;
    const int wave = tid >> 6;     // 0..7
    const int l15 = lane & 15;
    const int l4 = lane >> 4;      // 0..3
    const int wm2 = wave >> 2;     // 0..1 -> row block *128 (= A half read)
    const int wn4 = wave & 3;      // 0..3 -> col block *64

    // Bijective XCD swizzle: 256 blocks, each XCD owns a 4x8 tile sub-grid.
    const int bid = blockIdx.x;
    const int xcd = bid & 7;
    const int idx = bid >> 3;                       // 0..31
    const int trow = (xcd >> 1) * 4 + (idx >> 3);   // 0..15
    const int tcol = (xcd & 1) * 8 + (idx & 7);     // 0..15
    const int bm0 = trow * 256;
    const int bn0 = tcol * 256;

    // Stage unit = one tensor-half: 128 rows x 64 k x 2B = 16KB = 1024 chunks;
    // li = i*512 + tid: row = li>>3, cpos = li&7, global chunk g = cpos^(row&7).
    const unsigned short* gA[2];
    const unsigned short* gB[2];
    int lo[2];
#pragma unroll
    for (int i = 0; i < 2; ++i) {
        int li = i * 512 + tid;
        int row = li >> 3;
        int g = (li & 7) ^ (row & 7);
        gA[i] = A + (size_t)(bm0 + row) * K_LOCAL + g * 8;
        gB[i] = B + (size_t)(bn0 + row) * K_LOCAL + g * 8;
        lo[i] = li * 8;  // ushort units
    }

    auto stageA = [&](int t, int buf, int h) {
        const size_t off = (size_t)(t >> 4) * ((size_t)M_DIM * K_LOCAL)
                         + (size_t)((t & 15) << 6) + (size_t)h * (128 * K_LOCAL);
        unsigned short* l = &As[buf][h][0][0];
        async_copy16(gA[0] + off, l + lo[0]);
        async_copy16(gA[1] + off, l + lo[1]);
    };
    auto stageB = [&](int t, int buf, int h) {
        const size_t off = (size_t)(t >> 4) * ((size_t)M_DIM * K_LOCAL)
                         + (size_t)((t & 15) << 6) + (size_t)h * (128 * K_LOCAL);
        unsigned short* l = &Bs[buf][h][0][0];
        async_copy16(gB[0] + off, l + lo[0]);
        async_copy16(gB[1] + off, l + lo[1]);
    };

    // Fragment reads: k-chunk c = ks*4 + l4 stored at c ^ (row&7); frag rows
    // are <mult of 16> + l15, so row&7 == l15&7.
    const int swzk0 = ((l4 + 0) ^ (l15 & 7)) * 8;  // ks = 0
    const int swzk1 = ((l4 + 4) ^ (l15 & 7)) * 8;  // ks = 1
    const int hb = wn4 >> 1;                        // B half for this wave
    const int brow_base = (wn4 & 1) * 64 + l15;     // B row within half

    f32x4 acc[8][4] = {};
    bf16x8 aR[8], a1R[8], b0R[4], b1R[4];

    auto LDA = [&](bf16x8* dst, int buf, int mh) {
#pragma unroll
        for (int m = 0; m < 4; ++m) {
            const unsigned short* rp = &As[buf][wm2][mh * 64 + m * 16 + l15][0];
            dst[m * 2 + 0] = *(const bf16x8*)(rp + swzk0);
            dst[m * 2 + 1] = *(const bf16x8*)(rp + swzk1);
        }
    };
    auto LDB = [&](bf16x8* dst, int buf, int nh) {
#pragma unroll
        for (int n = 0; n < 2; ++n) {
            const unsigned short* rp = &Bs[buf][hb][brow_base + nh * 32 + n * 16][0];
            dst[n * 2 + 0] = *(const bf16x8*)(rp + swzk0);
            dst[n * 2 + 1] = *(const bf16x8*)(rp + swzk1);
        }
    };
    auto MFMA16 = [&](const bf16x8* a, const bf16x8* b, int mh, int nh) {
        __builtin_amdgcn_s_setprio(1);
#pragma unroll
        for (int m = 0; m < 4; ++m)
#pragma unroll
            for (int n = 0; n < 2; ++n)
#pragma unroll
                for (int ks = 0; ks < 2; ++ks)
                    acc[mh * 4 + m][nh * 2 + n] = __builtin_amdgcn_mfma_f32_16x16x32_bf16(
                        a[m * 2 + ks], b[n * 2 + ks], acc[mh * 4 + m][nh * 2 + n], 0, 0, 0);
        __builtin_amdgcn_s_setprio(0);
    };

    // Prologue: stage both tiles fully, drain, pre-read Q00(0) frags.
    stageA(0, 0, 0); stageA(0, 0, 1); stageB(0, 0, 0); stageB(0, 0, 1);
    stageA(1, 1, 0); stageA(1, 1, 1); stageB(1, 1, 0); stageB(1, 1, 1);
    VM0(); BAR();
    LDA(aR, 0, 0); LDB(b0R, 0, 0);

    for (int i = 0; i < NT / 2; ++i) {
        const int t1 = 2 * i + 1;
        const int t2 = (2 * i + 2) & (NT - 1);
        const int t3 = (2 * i + 3) & (NT - 1);
        const bool notlast = (i + 1 < NT / 2);
        // P0: MFMA Q00(t) | reads b1(t) | stage A-half0(t1)
        stageA(t1, 1, 0);
        BAR();
        LDB(b1R, 0, 1);
        MFMA16(aR, b0R, 0, 0);
        BAR();
        // P1: Q01(t) | reads a1(t) | stage A-half1(t1)
        stageA(t1, 1, 1);
        BAR();
        LDA(a1R, 0, 1);
        MFMA16(aR, b1R, 0, 1);
        BAR();
        // P2: Q10(t) | stage B-half0(t2)  (b1(t) readers done by P1-exit)
        stageB(t2, 0, 0);
        BAR();
        MFMA16(a1R, b0R, 1, 0);
        BAR();
        // P3: Q11(t) | reads aR,b0(t1) | stage B-half1(t2) | vmcnt(4)
        stageB(t2, 0, 1);
        VM4();
        BAR();
        LDA(aR, 1, 0); LDB(b0R, 1, 0);
        MFMA16(a1R, b1R, 1, 1);
        BAR();
        // P4: Q00(t1) | reads b1(t1) | stage A-half0(t2)
        stageA(t2, 0, 0);
        BAR();
        LDB(b1R, 1, 1);
        MFMA16(aR, b0R, 0, 0);
        BAR();
        // P5: Q01(t1) | reads a1(t1) | stage A-half1(t2)
        stageA(t2, 0, 1);
        BAR();
        LDA(a1R, 1, 1);
        MFMA16(aR, b1R, 0, 1);
        BAR();
        // P6: Q10(t1) | stage B-half0(t3)
        stageB(t3, 1, 0);
        BAR();
        MFMA16(a1R, b0R, 1, 0);
        BAR();
        // P7: Q11(t1) | reads aR,b0(t2) | stage B-half1(t3) | vmcnt(4)
        stageB(t3, 1, 1);
        VM4();
        BAR();
        if (notlast) { LDA(aR, 0, 0); LDB(b0R, 0, 0); }
        MFMA16(a1R, b1R, 1, 1);
        BAR();
    }

    // Epilogue: C/D layout col = lane&15, row = (lane>>4)*4 + reg.
#pragma unroll
    for (int m = 0; m < 8; ++m) {
        int row0 = bm0 + wm2 * 128 + m * 16 + l4 * 4;
#pragma unroll
        for (int n = 0; n < 4; ++n) {
            int col = bn0 + wn4 * 64 + n * 16 + l15;
#pragma unroll
            for (int rr = 0; rr < 4; ++rr)
                C[(size_t)(row0 + rr) * N_DIM + col] = acc[m][n][rr];
        }
    }
}

// ---------- Fallback (ws too small): naive fp32 tiled GEMM ----------
__global__ void gemm_naive(const float* __restrict__ A, const float* __restrict__ B,
                           float* __restrict__ C) {
    __shared__ float As[16][17];
    __shared__ float Bs[16][17];
    int tx = threadIdx.x, ty = threadIdx.y;
    int m = blockIdx.y * 16 + ty;
    int n0 = blockIdx.x * 16;
    float accv = 0.f;
    for (int kt = 0; kt < K_DIM; kt += 16) {
        int r = kt >> 10;
        int k = (kt & 1023) + tx;
        As[ty][tx] = A[((size_t)r * M_DIM + m) * K_LOCAL + k];
        Bs[ty][tx] = B[((size_t)r * N_DIM + (n0 + ty)) * K_LOCAL + k];
        __syncthreads();
#pragma unroll
        for (int kk = 0; kk < 16; ++kk) accv += As[ty][kk] * Bs[tx][kk];
        __syncthreads();
    }
    C[(size_t)m * N_DIM + n0 + tx] = accv;
}

extern "C" void kernel_launch(void* const* d_in, const int* in_sizes, int n_in,
                              void* d_out, int out_size, void* d_ws, size_t ws_size,
                              hipStream_t stream) {
    const float* inp = (const float*)d_in[0];
    const float* wgt = (const float*)d_in[1];
    float* out = (float*)d_out;

    const size_t elems = (size_t)M_DIM * K_DIM;              // 33,554,432 per tensor
    const size_t need = 2 * elems * sizeof(unsigned short);  // 128 MiB

    if (ws_size >= need) {
        unsigned short* Abf = (unsigned short*)d_ws;
        unsigned short* Bbf = Abf + elems;
        const int bpt = (int)(elems / 4096);      // 8192 blocks per tensor
        convert_cast<<<bpt * 2, 256, 0, stream>>>(inp, Abf, wgt, Bbf, bpt);
        gemm_bf16<<<256, 512, 0, stream>>>(Abf, Bbf, out);
    } else {
        dim3 grid(N_DIM / 16, M_DIM / 16);
        dim3 block(16, 16);
        gemm_naive<<<grid, block, 0, stream>>>(inp, wgt, out);
    }
}

// Round 6
// 472.846 us; speedup vs baseline: 1.3144x; 1.0958x over previous
//
#include <hip/hip_runtime.h>
#include <cstdint>
#include <cstddef>

// C[4096,4096] = sum_r input[r] @ weight[r]^T  == GEMM M=N=4096, K=8192, fp32 out.
// Phase 1: fp32 -> bf16 cast, R0 version (nontemporal loads keep the dead fp32
//          source OUT of L3 so the bf16 workspace stays L3-resident).
// Phase 2: R10: deep-prefetch 8-phase GEMM. R4 = m201 template but binding
//          vmcnt wait covered only ~2 phases of load latency (operands NOT
//          L3-resident here, unlike m201) -> waits block on HBM. New stage
//          slots give EVERY unit 6-7 phases stage->consume lead within the
//          same 2-buffer LDS (regions free much earlier than R4 used them):
//          P0:A1(t1) P1:B0(t2) P2:A0(t2) P3:B1(t2) P4:A1(t2) P5:B0(t3)
//          P6:A0(t3) P7:B1(t3); vmcnt(6) at P3/P7 (retires exactly 8 loads;
//          ledger closed). Reads stay in their consuming phase (R5's
//          read-ahead spilled: VGPR 128 + 16MB scratch, reverted).

#define M_DIM 4096
#define N_DIM 4096
#define K_DIM 8192
#define K_LOCAL 1024
#define RANKS 8
#define NT 128  // K-tiles: RANKS * (K_LOCAL/64)

typedef __bf16 bf16x8 __attribute__((ext_vector_type(8)));
typedef float f32x4 __attribute__((ext_vector_type(4)));

__device__ __forceinline__ unsigned short f2bf(float f) {
    unsigned int u = __float_as_uint(f);
    unsigned int r = (u + 0x7fffu + ((u >> 16) & 1u)) >> 16;
    return (unsigned short)r;
}

// ---------- Phase 1: linear fp32 -> bf16 cast (R0 version) ----------
__global__ __launch_bounds__(256) void convert_cast(
    const float* __restrict__ srcA, unsigned short* __restrict__ dstA,
    const float* __restrict__ srcB, unsigned short* __restrict__ dstB,
    int blocks_per_tensor) {
    const float* src = srcA;
    unsigned short* dst = dstA;
    int b = blockIdx.x;
    if (b >= blocks_per_tensor) { b -= blocks_per_tensor; src = srcB; dst = dstB; }
    size_t base = (size_t)b * 4096 + threadIdx.x * 4;
#pragma unroll
    for (int i = 0; i < 4; ++i) {
        size_t e = base + i * 1024;
        f32x4 v = __builtin_nontemporal_load((const f32x4*)(src + e));
        ushort4 o;
        o.x = f2bf(v.x); o.y = f2bf(v.y); o.z = f2bf(v.z); o.w = f2bf(v.w);
        *(ushort4*)(dst + e) = o;
    }
}

// ---------- Phase 2: 256^2 deep-prefetch 8-phase bf16 MFMA GEMM ----------
__device__ __forceinline__ void async_copy16(const unsigned short* g, unsigned short* l) {
    __builtin_amdgcn_global_load_lds(
        (const __attribute__((address_space(1))) void*)g,
        (__attribute__((address_space(3))) void*)l,
        16, 0, 0);
}

#define VM6()   asm volatile("s_waitcnt vmcnt(6)" ::: "memory")
#define VM0()   asm volatile("s_waitcnt vmcnt(0)" ::: "memory")
#define LGKM0() asm volatile("s_waitcnt lgkmcnt(0)" ::: "memory")
#define BAR()   __builtin_amdgcn_s_barrier()

__global__ __launch_bounds__(512, 2) void gemm_bf16(
    const unsigned short* __restrict__ A,  // [R, M, K_LOCAL] bf16
    const unsigned short* __restrict__ B,  // [R, N, K_LOCAL] bf16
    float* __restrict__ C) {               // [M, N] fp32
    // Per-tensor-half regions: [buf][rowhalf][128 rows][64 k] (128B rows).
    // 16B chunk c of row r stored at chunk c ^ (r & 7) (0 conflicts, R3-R5).
    __shared__ __align__(16) unsigned short As[2][2][128][64];
    __shared__ __align__(16) unsigned short Bs[2][2][128][64];

    const int tid = threadIdx.x;   // 0..511
    const int lane = tid & 63;
    const int wave = tid >> 6;     // 0..7
    const int l15 = lane & 15;
    const int l4 = lane >> 4;      // 0..3
    const int wm2 = wave >> 2;     // 0..1 -> row block *128 (= A half read)
    const int wn4 = wave & 3;      // 0..3 -> col block *64

    // Bijective XCD swizzle: 256 blocks, each XCD owns a 4x8 tile sub-grid.
    const int bid = blockIdx.x;
    const int xcd = bid & 7;
    const int idx = bid >> 3;                       // 0..31
    const int trow = (xcd >> 1) * 4 + (idx >> 3);   // 0..15
    const int tcol = (xcd & 1) * 8 + (idx & 7);     // 0..15
    const int bm0 = trow * 256;
    const int bn0 = tcol * 256;

    // Stage unit = one tensor-half: 128 rows x 64 k x 2B = 16KB = 1024 chunks;
    // li = i*512 + tid: row = li>>3, cpos = li&7, global chunk g = cpos^(row&7).
    const unsigned short* gA[2];
    const unsigned short* gB[2];
    int lo[2];
#pragma unroll
    for (int i = 0; i < 2; ++i) {
        int li = i * 512 + tid;
        int row = li >> 3;
        int g = (li & 7) ^ (row & 7);
        gA[i] = A + (size_t)(bm0 + row) * K_LOCAL + g * 8;
        gB[i] = B + (size_t)(bn0 + row) * K_LOCAL + g * 8;
        lo[i] = li * 8;  // ushort units
    }

    auto stageA = [&](int t, int buf, int h) {
        const size_t off = (size_t)(t >> 4) * ((size_t)M_DIM * K_LOCAL)
                         + (size_t)((t & 15) << 6) + (size_t)h * (128 * K_LOCAL);
        unsigned short* l = &As[buf][h][0][0];
        async_copy16(gA[0] + off, l + lo[0]);
        async_copy16(gA[1] + off, l + lo[1]);
    };
    auto stageB = [&](int t, int buf, int h) {
        const size_t off = (size_t)(t >> 4) * ((size_t)M_DIM * K_LOCAL)
                         + (size_t)((t & 15) << 6) + (size_t)h * (128 * K_LOCAL);
        unsigned short* l = &Bs[buf][h][0][0];
        async_copy16(gB[0] + off, l + lo[0]);
        async_copy16(gB[1] + off, l + lo[1]);
    };

    // Fragment reads: k-chunk c = ks*4 + l4 stored at c ^ (row&7); frag rows
    // are <mult of 16> + l15, so row&7 == l15&7.
    const int swzk0 = ((l4 + 0) ^ (l15 & 7)) * 8;  // ks = 0
    const int swzk1 = ((l4 + 4) ^ (l15 & 7)) * 8;  // ks = 1
    const int hb = wn4 >> 1;                        // B half for this wave
    const int brow_base = (wn4 & 1) * 64 + l15;     // B row within half

    f32x4 acc[8][4] = {};
    bf16x8 aR[8], a1R[8], b0R[4], b1R[4];

    auto LDA = [&](bf16x8* dst, int buf, int mh) {
#pragma unroll
        for (int m = 0; m < 4; ++m) {
            const unsigned short* rp = &As[buf][wm2][mh * 64 + m * 16 + l15][0];
            dst[m * 2 + 0] = *(const bf16x8*)(rp + swzk0);
            dst[m * 2 + 1] = *(const bf16x8*)(rp + swzk1);
        }
    };
    auto LDB = [&](bf16x8* dst, int buf, int nh) {
#pragma unroll
        for (int n = 0; n < 2; ++n) {
            const unsigned short* rp = &Bs[buf][hb][brow_base + nh * 32 + n * 16][0];
            dst[n * 2 + 0] = *(const bf16x8*)(rp + swzk0);
            dst[n * 2 + 1] = *(const bf16x8*)(rp + swzk1);
        }
    };
    auto MFMA16 = [&](const bf16x8* a, const bf16x8* b, int mh, int nh) {
        __builtin_amdgcn_s_setprio(1);
#pragma unroll
        for (int m = 0; m < 4; ++m)
#pragma unroll
            for (int n = 0; n < 2; ++n)
#pragma unroll
                for (int ks = 0; ks < 2; ++ks)
                    acc[mh * 4 + m][nh * 2 + n] = __builtin_amdgcn_mfma_f32_16x16x32_bf16(
                        a[m * 2 + ks], b[n * 2 + ks], acc[mh * 4 + m][nh * 2 + n], 0, 0, 0);
        __builtin_amdgcn_s_setprio(0);
    };

    // Prologue: t0 all 4 units (8 loads), then B0/A0/B1 of t1 (6 loads).
    // VM6 retires exactly t0's 8; {B0,A0,B1}(t1) stay in flight -> steady state.
    stageA(0, 0, 0); stageA(0, 0, 1); stageB(0, 0, 0); stageB(0, 0, 1);
    stageB(1, 1, 0); stageA(1, 1, 0); stageB(1, 1, 1);
    VM6(); BAR();

    for (int i = 0; i < NT / 2; ++i) {
        const int t1 = 2 * i + 1;
        const int t2 = (2 * i + 2) & (NT - 1);
        const int t3 = (2 * i + 3) & (NT - 1);
        // P0: Q00(t) | stage A1(t1)  [buf1.A1 read last at prev P6]
        LDA(aR, 0, 0); LDB(b0R, 0, 0); stageA(t1, 1, 1);
        BAR(); LGKM0(); MFMA16(aR, b0R, 0, 0); BAR();
        // P1: Q01(t) | stage B0(t2)  [buf0.B0 read at P0]
        LDB(b1R, 0, 1); stageB(t2, 0, 0);
        BAR(); LGKM0(); MFMA16(aR, b1R, 0, 1); BAR();
        // P2: Q10(t) | stage A0(t2)  [buf0.A0 read at P0]
        LDA(a1R, 0, 1); stageA(t2, 0, 0);
        BAR(); LGKM0(); MFMA16(a1R, b0R, 1, 0); BAR();
        // P3: Q11(t) | stage B1(t2)  [buf0.B1 read at P1] | vmcnt(6)
        stageB(t2, 0, 1);
        BAR(); MFMA16(a1R, b1R, 1, 1); VM6(); BAR();
        // P4: Q00(t1) | stage A1(t2) [buf0.A1 read at P2]
        LDA(aR, 1, 0); LDB(b0R, 1, 0); stageA(t2, 0, 1);
        BAR(); LGKM0(); MFMA16(aR, b0R, 0, 0); BAR();
        // P5: Q01(t1) | stage B0(t3) [buf1.B0 read at P4]
        LDB(b1R, 1, 1); stageB(t3, 1, 0);
        BAR(); LGKM0(); MFMA16(aR, b1R, 0, 1); BAR();
        // P6: Q10(t1) | stage A0(t3) [buf1.A0 read at P4]
        LDA(a1R, 1, 1); stageA(t3, 1, 0);
        BAR(); LGKM0(); MFMA16(a1R, b0R, 1, 0); BAR();
        // P7: Q11(t1) | stage B1(t3) [buf1.B1 read at P5] | vmcnt(6)
        stageB(t3, 1, 1);
        BAR(); MFMA16(a1R, b1R, 1, 1); VM6(); BAR();
    }
    VM0();  // drain outstanding DMA before exit

    // Epilogue: C/D layout col = lane&15, row = (lane>>4)*4 + reg.
#pragma unroll
    for (int m = 0; m < 8; ++m) {
        int row0 = bm0 + wm2 * 128 + m * 16 + l4 * 4;
#pragma unroll
        for (int n = 0; n < 4; ++n) {
            int col = bn0 + wn4 * 64 + n * 16 + l15;
#pragma unroll
            for (int rr = 0; rr < 4; ++rr)
                C[(size_t)(row0 + rr) * N_DIM + col] = acc[m][n][rr];
        }
    }
}

// ---------- Fallback (ws too small): naive fp32 tiled GEMM ----------
__global__ void gemm_naive(const float* __restrict__ A, const float* __restrict__ B,
                           float* __restrict__ C) {
    __shared__ float As[16][17];
    __shared__ float Bs[16][17];
    int tx = threadIdx.x, ty = threadIdx.y;
    int m = blockIdx.y * 16 + ty;
    int n0 = blockIdx.x * 16;
    float accv = 0.f;
    for (int kt = 0; kt < K_DIM; kt += 16) {
        int r = kt >> 10;
        int k = (kt & 1023) + tx;
        As[ty][tx] = A[((size_t)r * M_DIM + m) * K_LOCAL + k];
        Bs[ty][tx] = B[((size_t)r * N_DIM + (n0 + ty)) * K_LOCAL + k];
        __syncthreads();
#pragma unroll
        for (int kk = 0; kk < 16; ++kk) accv += As[ty][kk] * Bs[tx][kk];
        __syncthreads();
    }
    C[(size_t)m * N_DIM + n0 + tx] = accv;
}

extern "C" void kernel_launch(void* const* d_in, const int* in_sizes, int n_in,
                              void* d_out, int out_size, void* d_ws, size_t ws_size,
                              hipStream_t stream) {
    const float* inp = (const float*)d_in[0];
    const float* wgt = (const float*)d_in[1];
    float* out = (float*)d_out;

    const size_t elems = (size_t)M_DIM * K_DIM;              // 33,554,432 per tensor
    const size_t need = 2 * elems * sizeof(unsigned short);  // 128 MiB

    if (ws_size >= need) {
        unsigned short* Abf = (unsigned short*)d_ws;
        unsigned short* Bbf = Abf + elems;
        const int bpt = (int)(elems / 4096);      // 8192 blocks per tensor
        convert_cast<<<bpt * 2, 256, 0, stream>>>(inp, Abf, wgt, Bbf, bpt);
        gemm_bf16<<<256, 512, 0, stream>>>(Abf, Bbf, out);
    } else {
        dim3 grid(N_DIM / 16, M_DIM / 16);
        dim3 block(16, 16);
        gemm_naive<<<grid, block, 0, stream>>>(inp, wgt, out);
    }
}